// Round 1
// baseline (62626.642 us; speedup 1.0000x reference)
//
#include <hip/hip_runtime.h>
#include <hip/hip_bf16.h>

// Problem constants (match reference)
#define BB 32
#define TT 512
#define NN 1024
#define RR 4
#define II 8
#define DT_C 0.1f

// Tiling: each block handles ROWS rows of one batch; 256 threads = 4 waves,
// one wave per row at a time (coalesced 256B column-strided reads).
#define NBLK 32
#define ROWS (NN / NBLK)   // 32

__global__ __launch_bounds__(256) void k_initP(float* __restrict__ P) {
    const size_t total = (size_t)BB * NN * NN;
    const size_t stride = (size_t)gridDim.x * blockDim.x;
    for (size_t k = (size_t)blockIdx.x * blockDim.x + threadIdx.x; k < total; k += stride) {
        size_t pos = k % ((size_t)NN * NN);
        int i = (int)(pos / NN);
        int j = (int)(pos % NN);
        P[k] = (i == j) ? 0.1f : 0.0f;
    }
}

// step1: r = tanh(x); Pr = P@r; Jr = J@r; z = n^T r; rPr = sum r*Pr (atomic per block)
__global__ __launch_bounds__(256) void k_step1(
    const float* __restrict__ P, const float* __restrict__ x,
    const float* __restrict__ J, const float* __restrict__ nmat,
    float* __restrict__ Pr, float* __restrict__ Jr,
    float* __restrict__ zbuf, float* __restrict__ rPrAcc)
{
    const int b   = blockIdx.x / NBLK;
    const int blk = blockIdx.x % NBLK;
    const int tid = threadIdx.x;
    const int lane = tid & 63;
    const int wave = tid >> 6;

    __shared__ float r_sh[NN];
    __shared__ float rpr_sh[4];

    for (int j = tid; j < NN; j += 256) r_sh[j] = tanhf(x[b * NN + j]);
    __syncthreads();

    float rprPartial = 0.0f;
    for (int rr = wave; rr < ROWS; rr += 4) {
        const int row = blk * ROWS + rr;
        const float* __restrict__ Prow = P + ((size_t)b * NN + row) * NN;
        const float* __restrict__ Jrow = J + ((size_t)b * NN + row) * NN;
        float aP = 0.0f, aJ = 0.0f;
        for (int j = lane; j < NN; j += 64) {
            const float rv = r_sh[j];
            aP = fmaf(Prow[j], rv, aP);
            aJ = fmaf(Jrow[j], rv, aJ);
        }
        for (int off = 32; off; off >>= 1) {
            aP += __shfl_down(aP, off, 64);
            aJ += __shfl_down(aJ, off, 64);
        }
        if (lane == 0) {
            Pr[b * NN + row] = aP;
            Jr[b * NN + row] = aJ;
            rprPartial = fmaf(r_sh[row], aP, rprPartial);
        }
    }
    if (lane == 0) rpr_sh[wave] = rprPartial;
    __syncthreads();
    if (tid == 0) {
        atomicAdd(&rPrAcc[b], rpr_sh[0] + rpr_sh[1] + rpr_sh[2] + rpr_sh[3]);
    }

    // z = n^T r  (only blk 0 of each batch; wave k computes z[k])
    if (blk == 0 && wave < RR) {
        float acc = 0.0f;
        for (int i = lane; i < NN; i += 64) {
            acc = fmaf(nmat[((size_t)b * NN + i) * RR + wave], r_sh[i], acc);
        }
        for (int off = 32; off; off >>= 1) acc += __shfl_down(acc, off, 64);
        if (lane == 0) zbuf[b * RR + wave] = acc;
    }
}

// step2: c = 1/(1+rPr); P -= c Pr Pr^T; x_new = (1-dt)x + dt(Jr + m z + wIn u);
//        n -= c Pr (z - f_t)^T; write outputs
__global__ __launch_bounds__(256) void k_step2(
    float* __restrict__ P, float* __restrict__ x, float* __restrict__ nmat,
    const float* __restrict__ Pr, const float* __restrict__ Jr,
    const float* __restrict__ zbuf, const float* __restrict__ rPrAcc,
    const float* __restrict__ m, const float* __restrict__ wIn,
    const float* __restrict__ inputs, const float* __restrict__ f,
    float* __restrict__ outx, float* __restrict__ outz, int t)
{
    const int b   = blockIdx.x / NBLK;
    const int blk = blockIdx.x % NBLK;
    const int tid = threadIdx.x;
    const int lane = tid & 63;
    const int wave = tid >> 6;

    __shared__ float Pr_sh[NN];
    __shared__ float zsh[RR];
    __shared__ float zerr[RR];
    __shared__ float ush[II];

    for (int j = tid; j < NN; j += 256) Pr_sh[j] = Pr[b * NN + j];
    if (tid < RR) {
        const float zv = zbuf[b * RR + tid];
        zsh[tid]  = zv;
        zerr[tid] = zv - f[((size_t)b * TT + t) * RR + tid];
    }
    if (tid >= 64 && tid < 64 + II) {
        ush[tid - 64] = inputs[((size_t)b * TT + t) * II + (tid - 64)];
    }
    __syncthreads();

    const float c = 1.0f / (1.0f + rPrAcc[b]);

    // rank-1 update of P rows owned by this block
    for (int rr = wave; rr < ROWS; rr += 4) {
        const int row = blk * ROWS + rr;
        float* __restrict__ Prow = P + ((size_t)b * NN + row) * NN;
        const float cpr = c * Pr_sh[row];
        for (int j = lane; j < NN; j += 64) {
            Prow[j] = fmaf(-cpr, Pr_sh[j], Prow[j]);
        }
    }

    // x and n updates: one thread per row
    if (tid < ROWS) {
        const int row = blk * ROWS + tid;
        float acc = Jr[b * NN + row];
        #pragma unroll
        for (int k = 0; k < RR; ++k)
            acc = fmaf(m[((size_t)b * NN + row) * RR + k], zsh[k], acc);
        #pragma unroll
        for (int q = 0; q < II; ++q)
            acc = fmaf(wIn[((size_t)b * NN + row) * II + q], ush[q], acc);
        const float xo = x[b * NN + row];
        const float xn = (1.0f - DT_C) * xo + DT_C * acc;
        x[b * NN + row] = xn;
        outx[((size_t)b * TT + t) * NN + row] = xn;

        const float cpr = c * Pr_sh[row];
        #pragma unroll
        for (int k = 0; k < RR; ++k) {
            nmat[((size_t)b * NN + row) * RR + k] -= cpr * zerr[k];
        }
    }
    if (blk == 0 && tid < RR) {
        outz[((size_t)b * TT + t) * RR + tid] = zsh[tid];
    }
}

extern "C" void kernel_launch(void* const* d_in, const int* in_sizes, int n_in,
                              void* d_out, int out_size, void* d_ws, size_t ws_size,
                              hipStream_t stream) {
    const float* inputs = (const float*)d_in[0];   // (B,T,I,1)
    const float* f      = (const float*)d_in[1];   // (B,T,R,1)
    const float* J      = (const float*)d_in[2];   // (B,N,N)
    const float* wIn    = (const float*)d_in[3];   // (B,N,I)
    const float* m      = (const float*)d_in[4];   // (B,N,R)

    float* outx = (float*)d_out;                       // (B,T,N)
    float* outz = outx + (size_t)BB * TT * NN;         // (B,T,R)

    float* ws = (float*)d_ws;
    size_t off = 0;
    float* P    = ws + off; off += (size_t)BB * NN * NN;  // 128 MB
    float* x    = ws + off; off += (size_t)BB * NN;
    float* nm   = ws + off; off += (size_t)BB * NN * RR;
    float* Pr   = ws + off; off += (size_t)BB * NN;
    float* Jr   = ws + off; off += (size_t)BB * NN;
    float* zb   = ws + off; off += (size_t)BB * RR;
    float* rpr  = ws + off; off += (size_t)BB * TT;

    hipMemsetAsync(x,  0, (size_t)BB * NN * sizeof(float), stream);
    hipMemsetAsync(nm, 0, (size_t)BB * NN * RR * sizeof(float), stream);
    hipMemsetAsync(rpr,0, (size_t)BB * TT * sizeof(float), stream);
    k_initP<<<4096, 256, 0, stream>>>(P);

    for (int t = 0; t < TT; ++t) {
        k_step1<<<BB * NBLK, 256, 0, stream>>>(P, x, J, nm, Pr, Jr, zb,
                                               rpr + (size_t)t * BB);
        k_step2<<<BB * NBLK, 256, 0, stream>>>(P, x, nm, Pr, Jr, zb,
                                               rpr + (size_t)t * BB,
                                               m, wIn, inputs, f, outx, outz, t);
    }
}

// Round 2
// 24991.997 us; speedup vs baseline: 2.5059x; 2.5059x over previous
//
#include <hip/hip_runtime.h>
#include <hip/hip_bf16.h>

// Problem constants (match reference)
#define BB 32
#define TT 512
#define NN 1024
#define RR 4
#define II 8
#define DT_C 0.1f

// kernel A tiling: NBLK blocks of J-rows + VBLK blocks of V-columns per batch
#define NBLK 32
#define ROWS (NN / NBLK)   // 32
#define VBLK 16

// kernel A: r = tanh(x); Jr = J@r; a = V^T r; z = n^T r;
//           sig += 0.1|r|^2 - |a|^2   (== r^T P r, since P = 0.1 I - V V^T)
__global__ __launch_bounds__(256) void kA(
    const float* __restrict__ x, const float* __restrict__ J,
    const float* __restrict__ V, const float* __restrict__ nmat,
    float* __restrict__ r_out, float* __restrict__ a_out,
    float* __restrict__ Jr, float* __restrict__ zbuf,
    float* __restrict__ sig, int t)
{
    const int b   = blockIdx.x / (NBLK + VBLK);
    const int blk = blockIdx.x % (NBLK + VBLK);
    const int tid  = threadIdx.x;
    const int lane = tid & 63;
    const int wave = tid >> 6;

    __shared__ float r_sh[NN];
    __shared__ float red_sh[4];

    for (int j = tid; j < NN; j += 256) {
        const float rv = tanhf(x[b * NN + j]);
        r_sh[j] = rv;
        if (blk == 0) r_out[b * NN + j] = rv;
    }
    __syncthreads();

    const float4* r4 = (const float4*)r_sh;

    if (blk < NBLK) {
        // Jr rows
        for (int rr = wave; rr < ROWS; rr += 4) {
            const int row = blk * ROWS + rr;
            const float4* __restrict__ Jrow = (const float4*)(J + ((size_t)b * NN + row) * NN);
            float acc = 0.0f;
            for (int k = lane; k < NN / 4; k += 64) {
                const float4 jv = Jrow[k], rv = r4[k];
                acc = fmaf(jv.x, rv.x, acc); acc = fmaf(jv.y, rv.y, acc);
                acc = fmaf(jv.z, rv.z, acc); acc = fmaf(jv.w, rv.w, acc);
            }
            for (int off = 32; off; off >>= 1) acc += __shfl_down(acc, off, 64);
            if (lane == 0) Jr[b * NN + row] = acc;
        }
        if (blk == 0) {
            // 0.1 |r|^2
            float p = 0.0f;
            for (int j = tid; j < NN; j += 256) p = fmaf(r_sh[j], r_sh[j], p);
            for (int off = 32; off; off >>= 1) p += __shfl_down(p, off, 64);
            if (lane == 0) red_sh[wave] = p;
            __syncthreads();
            if (tid == 0)
                atomicAdd(&sig[b], 0.1f * (red_sh[0] + red_sh[1] + red_sh[2] + red_sh[3]));
            // z = n^T r
            if (wave < RR) {
                float acc = 0.0f;
                for (int i2 = lane; i2 < NN; i2 += 64)
                    acc = fmaf(nmat[((size_t)b * NN + i2) * RR + wave], r_sh[i2], acc);
                for (int off = 32; off; off >>= 1) acc += __shfl_down(acc, off, 64);
                if (lane == 0) zbuf[b * RR + wave] = acc;
            }
        }
    } else {
        // a_s = v_s . r  for columns s = wid, wid+64, ...
        const int vb  = blk - NBLK;
        const int wid = vb * 4 + wave;       // 0..63
        float negsum = 0.0f;
        for (int s = wid; s < t; s += 64) {
            const float4* __restrict__ col = (const float4*)(V + ((size_t)b * TT + s) * NN);
            float acc = 0.0f;
            for (int k = lane; k < NN / 4; k += 64) {
                const float4 vv = col[k], rv = r4[k];
                acc = fmaf(vv.x, rv.x, acc); acc = fmaf(vv.y, rv.y, acc);
                acc = fmaf(vv.z, rv.z, acc); acc = fmaf(vv.w, rv.w, acc);
            }
            for (int off = 32; off; off >>= 1) acc += __shfl_down(acc, off, 64);
            if (lane == 0) {
                a_out[b * TT + s] = acc;
                negsum = fmaf(-acc, acc, negsum);
            }
        }
        if (lane == 0 && negsum != 0.0f) atomicAdd(&sig[b], negsum);
    }
}

// kernel B: c = 1/(1+rPr); Pr = 0.1 r - V a; append v_t = sqrt(c) Pr;
//           x_new = (1-dt)x + dt(Jr + m z + wIn u); n -= c Pr (z - f_t)^T; outputs
__global__ __launch_bounds__(256) void kB(
    float* __restrict__ V, const float* __restrict__ r,
    const float* __restrict__ a, const float* __restrict__ Jr,
    const float* __restrict__ zbuf, const float* __restrict__ sig,
    float* __restrict__ x, float* __restrict__ nmat,
    const float* __restrict__ m, const float* __restrict__ wIn,
    const float* __restrict__ inputs, const float* __restrict__ f,
    float* __restrict__ outx, float* __restrict__ outz, int t)
{
    const int b   = blockIdx.x >> 2;
    const int sub = blockIdx.x & 3;
    const int tid = threadIdx.x;
    const int i   = sub * 256 + tid;

    __shared__ float a_sh[TT];
    __shared__ float zsh[RR], esh[RR], ush[II];

    for (int s = tid; s < t; s += 256) a_sh[s] = a[b * TT + s];
    if (tid < RR) {
        const float zv = zbuf[b * RR + tid];
        zsh[tid] = zv;
        esh[tid] = zv - f[((size_t)b * TT + t) * RR + tid];
    }
    if (tid >= 64 && tid < 64 + II)
        ush[tid - 64] = inputs[((size_t)b * TT + t) * II + (tid - 64)];
    __syncthreads();

    const float c  = 1.0f / (1.0f + sig[b]);
    const float sq = sqrtf(c);
    const float rv = r[b * NN + i];

    const float* __restrict__ Vb = V + (size_t)b * TT * NN + i;
    float s0 = 0.f, s1 = 0.f, s2 = 0.f, s3 = 0.f;
    int s = 0;
    for (; s + 4 <= t; s += 4) {
        s0 = fmaf(Vb[(size_t)(s + 0) << 10], a_sh[s + 0], s0);
        s1 = fmaf(Vb[(size_t)(s + 1) << 10], a_sh[s + 1], s1);
        s2 = fmaf(Vb[(size_t)(s + 2) << 10], a_sh[s + 2], s2);
        s3 = fmaf(Vb[(size_t)(s + 3) << 10], a_sh[s + 3], s3);
    }
    for (; s < t; ++s) s0 = fmaf(Vb[(size_t)s << 10], a_sh[s], s0);
    const float pr = 0.1f * rv - ((s0 + s1) + (s2 + s3));

    V[((size_t)b * TT + t) * NN + i] = sq * pr;

    // x update
    float acc = Jr[b * NN + i];
    const float4 mv = *(const float4*)(m + ((size_t)b * NN + i) * RR);
    acc = fmaf(mv.x, zsh[0], acc); acc = fmaf(mv.y, zsh[1], acc);
    acc = fmaf(mv.z, zsh[2], acc); acc = fmaf(mv.w, zsh[3], acc);
    const float4* __restrict__ wv = (const float4*)(wIn + ((size_t)b * NN + i) * II);
    const float4 w0 = wv[0], w1 = wv[1];
    acc = fmaf(w0.x, ush[0], acc); acc = fmaf(w0.y, ush[1], acc);
    acc = fmaf(w0.z, ush[2], acc); acc = fmaf(w0.w, ush[3], acc);
    acc = fmaf(w1.x, ush[4], acc); acc = fmaf(w1.y, ush[5], acc);
    acc = fmaf(w1.z, ush[6], acc); acc = fmaf(w1.w, ush[7], acc);
    const float xo = x[b * NN + i];
    const float xn = (1.0f - DT_C) * xo + DT_C * acc;
    x[b * NN + i] = xn;
    outx[((size_t)b * TT + t) * NN + i] = xn;

    // n update
    float4* __restrict__ np = (float4*)(nmat + ((size_t)b * NN + i) * RR);
    float4 nv = *np;
    const float cpr = c * pr;
    nv.x = fmaf(-cpr, esh[0], nv.x); nv.y = fmaf(-cpr, esh[1], nv.y);
    nv.z = fmaf(-cpr, esh[2], nv.z); nv.w = fmaf(-cpr, esh[3], nv.w);
    *np = nv;

    if (sub == 0 && tid < RR) outz[((size_t)b * TT + t) * RR + tid] = zsh[tid];
}

extern "C" void kernel_launch(void* const* d_in, const int* in_sizes, int n_in,
                              void* d_out, int out_size, void* d_ws, size_t ws_size,
                              hipStream_t stream) {
    const float* inputs = (const float*)d_in[0];   // (B,T,I,1)
    const float* f      = (const float*)d_in[1];   // (B,T,R,1)
    const float* J      = (const float*)d_in[2];   // (B,N,N)
    const float* wIn    = (const float*)d_in[3];   // (B,N,I)
    const float* m      = (const float*)d_in[4];   // (B,N,R)

    float* outx = (float*)d_out;                   // (B,T,N)
    float* outz = outx + (size_t)BB * TT * NN;     // (B,T,R)

    float* ws = (float*)d_ws;
    size_t off = 0;
    float* V    = ws + off; off += (size_t)BB * TT * NN;  // 64 MB, time-major columns
    float* x    = ws + off; off += (size_t)BB * NN;
    float* nm   = ws + off; off += (size_t)BB * NN * RR;
    float* rbuf = ws + off; off += (size_t)BB * NN;
    float* abuf = ws + off; off += (size_t)BB * TT;
    float* Jr   = ws + off; off += (size_t)BB * NN;
    float* zb   = ws + off; off += (size_t)BB * RR;
    float* rpr  = ws + off; off += (size_t)BB * TT;

    hipMemsetAsync(x,   0, (size_t)BB * NN * sizeof(float), stream);
    hipMemsetAsync(nm,  0, (size_t)BB * NN * RR * sizeof(float), stream);
    hipMemsetAsync(rpr, 0, (size_t)BB * TT * sizeof(float), stream);

    for (int t = 0; t < TT; ++t) {
        kA<<<BB * (NBLK + VBLK), 256, 0, stream>>>(x, J, V, nm, rbuf, abuf, Jr, zb,
                                                   rpr + (size_t)t * BB, t);
        kB<<<BB * 4, 256, 0, stream>>>(V, rbuf, abuf, Jr, zb,
                                       rpr + (size_t)t * BB,
                                       x, nm, m, wIn, inputs, f, outx, outz, t);
    }
}

// Round 3
// 14669.263 us; speedup vs baseline: 4.2692x; 1.7037x over previous
//
#include <hip/hip_runtime.h>
#include <hip/hip_bf16.h>

// Problem constants
#define BB 32
#define TT 512
#define NN 1024
#define RR 4
#define II 8
#define DT_C 0.1f

// kernel A tiling
#define NBLK 32
#define ROWS (NN / NBLK)   // 32
#define VBLK 16

typedef __attribute__((ext_vector_type(8))) unsigned short ushort8v;

__device__ __forceinline__ float bf2f(unsigned short u) {
    union { unsigned int ui; float f; } cv;
    cv.ui = ((unsigned int)u) << 16;
    return cv.f;
}
__device__ __forceinline__ unsigned short f2bf_rne(float x) {
    union { float f; unsigned int ui; } cv; cv.f = x;
    unsigned int u = cv.ui;
    u += 0x7FFFu + ((u >> 16) & 1u);
    return (unsigned short)(u >> 16);
}

// Permuted layout: position o in [0,1024) holds column col(o) = l + 64*(8g+e)
// where l=(o>>3)&63, g=o>>9, e=o&7. A wave reading ushort8 at index (g*64+lane)
// gets elements for columns lane+512g+64e, e=0..7 -> LDS r_sh reads are
// lane-consecutive (conflict-free).

__global__ __launch_bounds__(256) void k_convJ(const float* __restrict__ J,
                                               unsigned short* __restrict__ Jp) {
    const int row = blockIdx.x;            // 0 .. BB*NN-1 (flattened b*NN+row)
    const int tid = threadIdx.x;
    __shared__ float rowsh[NN];
    const float4* __restrict__ src = (const float4*)(J + (size_t)row * NN);
    float4* dst4 = (float4*)rowsh;
    for (int k = tid; k < NN / 4; k += 256) dst4[k] = src[k];
    __syncthreads();
    const int o0 = tid * 4;
    unsigned short out[4];
    #pragma unroll
    for (int j = 0; j < 4; ++j) {
        const int o = o0 + j;
        const int l = (o >> 3) & 63, g = o >> 9, e = o & 7;
        out[j] = f2bf_rne(rowsh[l + 64 * (8 * g + e)]);
    }
    uint2 w;
    w.x = (unsigned int)out[0] | ((unsigned int)out[1] << 16);
    w.y = (unsigned int)out[2] | ((unsigned int)out[3] << 16);
    *(uint2*)(Jp + (size_t)row * NN + o0) = w;
}

// kA: r = tanh(x); Jr = J@r; a = V^T r; z = n^T r; sigma partials
__global__ __launch_bounds__(256) void kA(
    const float* __restrict__ x, const unsigned short* __restrict__ Jp,
    const unsigned short* __restrict__ Vp, const float* __restrict__ nmat,
    float* __restrict__ r_out, float* __restrict__ a_out,
    float* __restrict__ Jr, float* __restrict__ zbuf,
    float* __restrict__ part, int t)
{
    const int b   = blockIdx.x / (NBLK + VBLK);
    const int blk = blockIdx.x % (NBLK + VBLK);
    const int tid = threadIdx.x, lane = tid & 63, wave = tid >> 6;

    __shared__ float r_sh[NN];
    __shared__ float red_sh[4];

    for (int j = tid; j < NN; j += 256) {
        const float rv = tanhf(x[b * NN + j]);
        r_sh[j] = rv;
        if (blk == 0) r_out[b * NN + j] = rv;
    }
    __syncthreads();

    if (blk < NBLK) {
        for (int rr = wave; rr < ROWS; rr += 4) {
            const int row = blk * ROWS + rr;
            const ushort8v* __restrict__ Jrow =
                (const ushort8v*)(Jp + ((size_t)b * NN + row) * NN);
            const ushort8v jv0 = Jrow[lane];
            const ushort8v jv1 = Jrow[64 + lane];
            float acc = 0.0f;
            #pragma unroll
            for (int e = 0; e < 8; ++e)
                acc = fmaf(bf2f(jv0[e]), r_sh[lane + 64 * e], acc);
            #pragma unroll
            for (int e = 0; e < 8; ++e)
                acc = fmaf(bf2f(jv1[e]), r_sh[lane + 512 + 64 * e], acc);
            for (int off = 32; off; off >>= 1) acc += __shfl_down(acc, off, 64);
            if (lane == 0) Jr[b * NN + row] = acc;
        }
        if (blk == 0) {
            float p = 0.0f;
            for (int j = tid; j < NN; j += 256) p = fmaf(r_sh[j], r_sh[j], p);
            for (int off = 32; off; off >>= 1) p += __shfl_down(p, off, 64);
            if (lane == 0) red_sh[wave] = p;
            __syncthreads();
            if (tid == 0)
                part[b * 72 + 64] = 0.1f * (red_sh[0] + red_sh[1] + red_sh[2] + red_sh[3]);
            if (wave < RR) {
                float acc = 0.0f;
                for (int i2 = lane; i2 < NN; i2 += 64)
                    acc = fmaf(nmat[((size_t)b * NN + i2) * RR + wave], r_sh[i2], acc);
                for (int off = 32; off; off >>= 1) acc += __shfl_down(acc, off, 64);
                if (lane == 0) zbuf[b * RR + wave] = acc;
            }
        }
    } else {
        const int wid = (blk - NBLK) * 4 + wave;   // 0..63
        float negsum = 0.0f;
        for (int s = wid; s < t; s += 64) {
            const ushort8v* __restrict__ col =
                (const ushort8v*)(Vp + ((size_t)b * TT + s) * NN);
            const ushort8v vv0 = col[lane];
            const ushort8v vv1 = col[64 + lane];
            float acc = 0.0f;
            #pragma unroll
            for (int e = 0; e < 8; ++e)
                acc = fmaf(bf2f(vv0[e]), r_sh[lane + 64 * e], acc);
            #pragma unroll
            for (int e = 0; e < 8; ++e)
                acc = fmaf(bf2f(vv1[e]), r_sh[lane + 512 + 64 * e], acc);
            for (int off = 32; off; off >>= 1) acc += __shfl_down(acc, off, 64);
            if (lane == 0) {
                a_out[b * TT + s] = acc;
                negsum = fmaf(-acc, acc, negsum);
            }
        }
        if (lane == 0) part[b * 72 + wid] = negsum;  // unconditional: zero when empty
    }
}

// kB: c = 1/(1+sigma); Pr = 0.1 r - V a; append v_t = sqrt(c) Pr (bf16);
//     x/n updates; outputs
__global__ __launch_bounds__(256) void kB(
    unsigned short* __restrict__ Vp, const float* __restrict__ r,
    const float* __restrict__ a, const float* __restrict__ Jr,
    const float* __restrict__ zbuf, const float* __restrict__ part,
    float* __restrict__ x, float* __restrict__ nmat,
    const float* __restrict__ m, const float* __restrict__ wIn,
    const float* __restrict__ inputs, const float* __restrict__ f,
    float* __restrict__ outx, float* __restrict__ outz, int t)
{
    const int b   = blockIdx.x >> 3;
    const int tb  = blockIdx.x & 7;
    const int tid = threadIdx.x;
    const int pl    = tid & 63;    // pair-lane
    const int slice = tid >> 6;    // 0..3

    __shared__ float a_sh[TT];
    __shared__ float ps[4][128];
    __shared__ float zsh[RR], esh[RR], ush[II];

    for (int s = tid; s < t; s += 256) a_sh[s] = a[b * TT + s];
    if (tid < RR) {
        const float zv = zbuf[b * RR + tid];
        zsh[tid] = zv;
        esh[tid] = zv - f[((size_t)b * TT + t) * RR + tid];
    }
    if (tid >= 64 && tid < 64 + II)
        ush[tid - 64] = inputs[((size_t)b * TT + t) * II + (tid - 64)];
    __syncthreads();

    const int p0 = (tb * 64 + pl) * 2;            // even permuted position
    const unsigned short* __restrict__ Vb = Vp + (size_t)b * TT * NN;

    const int s_begin = (t * slice) >> 2;
    const int s_end   = (t * (slice + 1)) >> 2;
    float acc0 = 0.0f, acc1 = 0.0f;
    #pragma unroll 4
    for (int s = s_begin; s < s_end; ++s) {
        const unsigned int w = *(const unsigned int*)(Vb + (size_t)s * NN + p0);
        const float av = a_sh[s];
        acc0 = fmaf(bf2f((unsigned short)(w & 0xFFFFu)), av, acc0);
        acc1 = fmaf(bf2f((unsigned short)(w >> 16)), av, acc1);
    }
    ps[slice][pl * 2]     = acc0;
    ps[slice][pl * 2 + 1] = acc1;
    __syncthreads();

    if (slice == 0) {
        const int l = (p0 >> 3) & 63, g = p0 >> 9, e = p0 & 7;
        const int i0 = l + 64 * (8 * g + e);
        const int i1 = i0 + 64;
        const float s0 = ps[0][pl * 2] + ps[1][pl * 2] + ps[2][pl * 2] + ps[3][pl * 2];
        const float s1 = ps[0][pl * 2 + 1] + ps[1][pl * 2 + 1] + ps[2][pl * 2 + 1] + ps[3][pl * 2 + 1];

        float sg = 0.0f;
        #pragma unroll
        for (int k = 0; k < 65; ++k) sg += part[b * 72 + k];
        const float c  = 1.0f / (1.0f + sg);
        const float sq = sqrtf(c);

        const float pr0 = 0.1f * r[b * NN + i0] - s0;
        const float pr1 = 0.1f * r[b * NN + i1] - s1;

        unsigned int wv = (unsigned int)f2bf_rne(sq * pr0) |
                          ((unsigned int)f2bf_rne(sq * pr1) << 16);
        *(unsigned int*)(Vp + ((size_t)b * TT + t) * NN + p0) = wv;

        #pragma unroll
        for (int which = 0; which < 2; ++which) {
            const int   i  = which ? i1 : i0;
            const float pr = which ? pr1 : pr0;
            float acc = Jr[b * NN + i];
            const float4 mv = *(const float4*)(m + ((size_t)b * NN + i) * RR);
            acc = fmaf(mv.x, zsh[0], acc); acc = fmaf(mv.y, zsh[1], acc);
            acc = fmaf(mv.z, zsh[2], acc); acc = fmaf(mv.w, zsh[3], acc);
            const float4* __restrict__ wp = (const float4*)(wIn + ((size_t)b * NN + i) * II);
            const float4 w0 = wp[0], w1 = wp[1];
            acc = fmaf(w0.x, ush[0], acc); acc = fmaf(w0.y, ush[1], acc);
            acc = fmaf(w0.z, ush[2], acc); acc = fmaf(w0.w, ush[3], acc);
            acc = fmaf(w1.x, ush[4], acc); acc = fmaf(w1.y, ush[5], acc);
            acc = fmaf(w1.z, ush[6], acc); acc = fmaf(w1.w, ush[7], acc);
            const float xo = x[b * NN + i];
            const float xn = (1.0f - DT_C) * xo + DT_C * acc;
            x[b * NN + i] = xn;
            outx[((size_t)b * TT + t) * NN + i] = xn;

            float4* __restrict__ np = (float4*)(nmat + ((size_t)b * NN + i) * RR);
            float4 nv = *np;
            const float cpr = c * pr;
            nv.x = fmaf(-cpr, esh[0], nv.x); nv.y = fmaf(-cpr, esh[1], nv.y);
            nv.z = fmaf(-cpr, esh[2], nv.z); nv.w = fmaf(-cpr, esh[3], nv.w);
            *np = nv;
        }
    }
    if (tb == 0 && tid < RR) outz[((size_t)b * TT + t) * RR + tid] = zsh[tid];
}

extern "C" void kernel_launch(void* const* d_in, const int* in_sizes, int n_in,
                              void* d_out, int out_size, void* d_ws, size_t ws_size,
                              hipStream_t stream) {
    const float* inputs = (const float*)d_in[0];   // (B,T,I,1)
    const float* f      = (const float*)d_in[1];   // (B,T,R,1)
    const float* J      = (const float*)d_in[2];   // (B,N,N)
    const float* wIn    = (const float*)d_in[3];   // (B,N,I)
    const float* m      = (const float*)d_in[4];   // (B,N,R)

    float* outx = (float*)d_out;                   // (B,T,N)
    float* outz = outx + (size_t)BB * TT * NN;     // (B,T,R)

    char* ws = (char*)d_ws;
    size_t off = 0;
    unsigned short* Jp = (unsigned short*)(ws + off); off += (size_t)BB * NN * NN * 2;  // 67 MB
    unsigned short* Vp = (unsigned short*)(ws + off); off += (size_t)BB * TT * NN * 2;  // 33.5 MB
    float* x    = (float*)(ws + off); off += (size_t)BB * NN * 4;
    float* nm   = (float*)(ws + off); off += (size_t)BB * NN * RR * 4;
    float* rbuf = (float*)(ws + off); off += (size_t)BB * NN * 4;
    float* abuf = (float*)(ws + off); off += (size_t)BB * TT * 4;
    float* Jrb  = (float*)(ws + off); off += (size_t)BB * NN * 4;
    float* zb   = (float*)(ws + off); off += (size_t)BB * RR * 4;
    float* part = (float*)(ws + off); off += (size_t)BB * 72 * 4;

    hipMemsetAsync(x,  0, (size_t)BB * NN * sizeof(float), stream);
    hipMemsetAsync(nm, 0, (size_t)BB * NN * RR * sizeof(float), stream);

    k_convJ<<<BB * NN, 256, 0, stream>>>(J, Jp);

    for (int t = 0; t < TT; ++t) {
        kA<<<BB * (NBLK + VBLK), 256, 0, stream>>>(x, Jp, Vp, nm, rbuf, abuf,
                                                   Jrb, zb, part, t);
        kB<<<BB * 8, 256, 0, stream>>>(Vp, rbuf, abuf, Jrb, zb, part,
                                       x, nm, m, wIn, inputs, f, outx, outz, t);
    }
}